// Round 1
// baseline (857.069 us; speedup 1.0000x reference)
//
#include <hip/hip_runtime.h>

// GCN 3-layer: per layer  h = (x * d_out^-1/2) @ W ; agg = scatter_sum_dst(h[src]) ;
//              out = agg * d_in^-1/2 + b ; relu (layers 0,1)
// Strategy: build CSR sorted by dst once per call (no f32 atomics in the hot path),
// f32 tiled GEMM with norm_src fused into A-load, wave-per-node aggregation with
// norm_dst+bias+relu fused into the epilogue.

#define WAVE 64

// ---------------- utility ----------------
__global__ void k_zero_i32(int* __restrict__ p, int n) {
    int i = blockIdx.x * blockDim.x + threadIdx.x;
    int stride = gridDim.x * blockDim.x;
    for (; i < n; i += stride) p[i] = 0;
}

// ---------------- degree histogram ----------------
__global__ void k_degrees(const int* __restrict__ src, const int* __restrict__ dst, int E,
                          int* __restrict__ deg_o, int* __restrict__ deg_i) {
    int i = blockIdx.x * blockDim.x + threadIdx.x;
    int stride = gridDim.x * blockDim.x;
    for (; i < E; i += stride) {
        atomicAdd(&deg_o[src[i]], 1);
        atomicAdd(&deg_i[dst[i]], 1);
    }
}

__global__ void k_norms(const int* __restrict__ deg_o, const int* __restrict__ deg_i,
                        float* __restrict__ ns, float* __restrict__ nd, int n) {
    int i = blockIdx.x * blockDim.x + threadIdx.x;
    if (i < n) {
        ns[i] = rsqrtf((float)max(deg_o[i], 1));
        nd[i] = rsqrtf((float)max(deg_i[i], 1));
    }
}

// ---------------- single-block exclusive scan (row_ptr) ----------------
__global__ __launch_bounds__(1024) void k_scan(const int* __restrict__ deg, int* __restrict__ rp, int n) {
    __shared__ int wsum[16];
    __shared__ int carry_s;
    const int tid = threadIdx.x;
    const int lane = tid & 63, wid = tid >> 6;
    if (tid == 0) carry_s = 0;
    __syncthreads();
    for (int base = 0; base < n; base += 1024) {
        int i = base + tid;
        int v = (i < n) ? deg[i] : 0;
        int x = v;
#pragma unroll
        for (int off = 1; off < 64; off <<= 1) {
            int t = __shfl_up(x, off, 64);
            if (lane >= off) x += t;
        }
        if (lane == 63) wsum[wid] = x;
        __syncthreads();
        int carry = carry_s;
        if (wid == 0) {
            int wv = (lane < 16) ? wsum[lane] : 0;
#pragma unroll
            for (int off = 1; off < 16; off <<= 1) {
                int t = __shfl_up(wv, off, 64);
                if (lane >= off) wv += t;
            }
            if (lane < 16) wsum[lane] = wv;
        }
        __syncthreads();
        int wave_off = (wid == 0) ? 0 : wsum[wid - 1];
        int incl = carry + wave_off + x;
        if (i < n) rp[i] = incl - v;  // exclusive
        __syncthreads();
        if (tid == 1023) carry_s = carry + wsum[15];
        __syncthreads();
    }
    if (tid == 0) rp[n] = carry_s;
}

// ---------------- CSR fill (sorted by dst) ----------------
__global__ void k_fill(const int* __restrict__ src, const int* __restrict__ dst, int E,
                       const int* __restrict__ rp, int* __restrict__ fill,
                       int* __restrict__ csr_src) {
    int i = blockIdx.x * blockDim.x + threadIdx.x;
    int stride = gridDim.x * blockDim.x;
    for (; i < E; i += stride) {
        int d = dst[i];
        int p = rp[d] + atomicAdd(&fill[d], 1);
        csr_src[p] = src[i];
    }
}

// ---------------- GEMM: C[n,BN] = (A[n,128] * ns[row]) @ W[128,BN] ----------------
template <int BN, int TM, int TN>
__global__ __launch_bounds__(256) void k_gemm(const float* __restrict__ A,
                                              const float* __restrict__ ns,
                                              const float* __restrict__ W,
                                              float* __restrict__ C, int n) {
    constexpr int BM = 64, BK = 32, K = 128;
    constexpr int TCOLS = BN / TN;       // 32 (BN=128) or 16 (BN=64)
    constexpr int TROWS = 256 / TCOLS;   // 8 or 16
    static_assert(TM == BM / TROWS, "tile mismatch");
    __shared__ float As[BK][BM + 4];     // transposed A tile
    __shared__ float Ws[BK][BN + 4];
    const int tid = threadIdx.x;
    const int row0 = blockIdx.x * BM;
    const int tc = tid % TCOLS, tr = tid / TCOLS;
    float acc[TM][TN] = {};
    for (int k0 = 0; k0 < K; k0 += BK) {
        // A tile: BM*BK/4 = 512 float4s, 2 per thread
#pragma unroll
        for (int f = 0; f < (BM * BK / 4) / 256; ++f) {
            int idx = tid + f * 256;
            int r = idx >> 3, c = idx & 7;
            float4 v = make_float4(0.f, 0.f, 0.f, 0.f);
            int gr = row0 + r;
            if (gr < n) {
                v = *(const float4*)(A + (size_t)gr * K + k0 + c * 4);
                float s = ns[gr];
                v.x *= s; v.y *= s; v.z *= s; v.w *= s;
            }
            As[c * 4 + 0][r] = v.x;
            As[c * 4 + 1][r] = v.y;
            As[c * 4 + 2][r] = v.z;
            As[c * 4 + 3][r] = v.w;
        }
        // W tile
#pragma unroll
        for (int f = 0; f < (BK * BN / 4) / 256; ++f) {
            int idx = tid + f * 256;
            int kr = idx / (BN / 4), c4 = idx % (BN / 4);
            float4 v = *(const float4*)(W + (size_t)(k0 + kr) * BN + c4 * 4);
            *(float4*)&Ws[kr][c4 * 4] = v;
        }
        __syncthreads();
#pragma unroll
        for (int kk = 0; kk < BK; ++kk) {
            float a[TM], w[TN];
#pragma unroll
            for (int m = 0; m < TM; ++m) a[m] = As[kk][tr * TM + m];
#pragma unroll
            for (int j = 0; j < TN; ++j) w[j] = Ws[kk][tc * TN + j];
#pragma unroll
            for (int m = 0; m < TM; ++m)
#pragma unroll
                for (int j = 0; j < TN; ++j) acc[m][j] += a[m] * w[j];
        }
        __syncthreads();
    }
#pragma unroll
    for (int m = 0; m < TM; ++m) {
        int gr = row0 + tr * TM + m;
        if (gr < n) *(float4*)(C + (size_t)gr * BN + tc * TN) = *(float4*)&acc[m][0];
    }
}

// ---------------- aggregation: one wave per node, D=128 (float2/lane) ----------------
template <bool RELU>
__global__ __launch_bounds__(256) void k_agg128(const float* __restrict__ H,
                                                const int* __restrict__ rp,
                                                const int* __restrict__ cs,
                                                const float* __restrict__ nd,
                                                const float* __restrict__ b,
                                                float* __restrict__ out, int n) {
    const int wid = threadIdx.x >> 6, lane = threadIdx.x & 63;
    const int node = blockIdx.x * 4 + wid;
    if (node >= n) return;
    const int beg = rp[node], end = rp[node + 1];
    float2 acc0 = make_float2(0.f, 0.f), acc1 = make_float2(0.f, 0.f);
    int e = beg;
    for (; e + 1 < end; e += 2) {
        int s0 = cs[e], s1 = cs[e + 1];
        float2 v0 = ((const float2*)(H + (size_t)s0 * 128))[lane];
        float2 v1 = ((const float2*)(H + (size_t)s1 * 128))[lane];
        acc0.x += v0.x; acc0.y += v0.y;
        acc1.x += v1.x; acc1.y += v1.y;
    }
    if (e < end) {
        int s0 = cs[e];
        float2 v0 = ((const float2*)(H + (size_t)s0 * 128))[lane];
        acc0.x += v0.x; acc0.y += v0.y;
    }
    const float sc = nd[node];
    float2 bb = ((const float2*)b)[lane];
    float ox = (acc0.x + acc1.x) * sc + bb.x;
    float oy = (acc0.y + acc1.y) * sc + bb.y;
    if (RELU) { ox = fmaxf(ox, 0.f); oy = fmaxf(oy, 0.f); }
    ((float2*)(out + (size_t)node * 128))[lane] = make_float2(ox, oy);
}

// ---------------- aggregation D=64 (1 float/lane), final layer, no relu ----------------
__global__ __launch_bounds__(256) void k_agg64(const float* __restrict__ H,
                                               const int* __restrict__ rp,
                                               const int* __restrict__ cs,
                                               const float* __restrict__ nd,
                                               const float* __restrict__ b,
                                               float* __restrict__ out, int n) {
    const int wid = threadIdx.x >> 6, lane = threadIdx.x & 63;
    const int node = blockIdx.x * 4 + wid;
    if (node >= n) return;
    const int beg = rp[node], end = rp[node + 1];
    float acc0 = 0.f, acc1 = 0.f;
    int e = beg;
    for (; e + 1 < end; e += 2) {
        int s0 = cs[e], s1 = cs[e + 1];
        acc0 += H[(size_t)s0 * 64 + lane];
        acc1 += H[(size_t)s1 * 64 + lane];
    }
    if (e < end) acc0 += H[(size_t)cs[e] * 64 + lane];
    float o = (acc0 + acc1) * nd[node] + b[lane];
    out[(size_t)node * 64 + lane] = o;
}

extern "C" void kernel_launch(void* const* d_in, const int* in_sizes, int n_in,
                              void* d_out, int out_size, void* d_ws, size_t ws_size,
                              hipStream_t stream) {
    const float* feat = (const float*)d_in[0];
    const int* ei = (const int*)d_in[1];
    const float* W0 = (const float*)d_in[2];
    const float* b0 = (const float*)d_in[3];
    const float* W1 = (const float*)d_in[4];
    const float* b1 = (const float*)d_in[5];
    const float* W2 = (const float*)d_in[6];
    const float* b2 = (const float*)d_in[7];
    float* out = (float*)d_out;

    const int N = in_sizes[0] / 128;   // 100000
    const int E = in_sizes[1] / 2;     // 1600000
    const int* src = ei;
    const int* dst = ei + E;

    // workspace layout (all offsets 16B-aligned)
    char* w = (char*)d_ws;
    float* norm_src = (float*)w; w += (size_t)N * 4;
    float* norm_dst = (float*)w; w += (size_t)N * 4;
    int* deg_o = (int*)w;        w += (size_t)N * 4;
    int* deg_i = (int*)w;        w += (size_t)N * 4;
    int* fill  = (int*)w;        w += (size_t)N * 4;   // deg_o,deg_i,fill contiguous
    int* rp    = (int*)w;        w += ((size_t)(N + 1) * 4 + 15) / 16 * 16;
    int* csr   = (int*)w;        w += (size_t)E * 4;
    float* bufA = (float*)w;     w += (size_t)N * 128 * 4;
    float* bufB = (float*)w;     // w += (size_t)N * 128 * 4;

    // 1. zero histograms + fill counters (3N contiguous ints)
    k_zero_i32<<<512, 256, 0, stream>>>(deg_o, 3 * N);
    // 2. degrees
    k_degrees<<<2048, 256, 0, stream>>>(src, dst, E, deg_o, deg_i);
    // 3. norms
    k_norms<<<(N + 255) / 256, 256, 0, stream>>>(deg_o, deg_i, norm_src, norm_dst, N);
    // 4. row_ptr = exclusive scan(deg_i)
    k_scan<<<1, 1024, 0, stream>>>(deg_i, rp, N);
    // 5. CSR fill
    k_fill<<<2048, 256, 0, stream>>>(src, dst, E, rp, fill, csr);

    const int gemm_grid = (N + 63) / 64;
    const int agg_grid = (N + 3) / 4;

    // layer 0
    k_gemm<128, 8, 4><<<gemm_grid, 256, 0, stream>>>(feat, norm_src, W0, bufA, N);
    k_agg128<true><<<agg_grid, 256, 0, stream>>>(bufA, rp, csr, norm_dst, b0, bufB, N);
    // layer 1
    k_gemm<128, 8, 4><<<gemm_grid, 256, 0, stream>>>(bufB, norm_src, W1, bufA, N);
    k_agg128<true><<<agg_grid, 256, 0, stream>>>(bufA, rp, csr, norm_dst, b1, bufB, N);
    // layer 2 (out dim 64, no relu)
    k_gemm<64, 4, 4><<<gemm_grid, 256, 0, stream>>>(bufB, norm_src, W2, bufA, N);
    k_agg64<<<agg_grid, 256, 0, stream>>>(bufA, rp, csr, norm_dst, b2, out, N);
}

// Round 5
// 600.978 us; speedup vs baseline: 1.4261x; 1.4261x over previous
//
#include <hip/hip_runtime.h>
#include <hip/hip_fp16.h>

// GCN 3-layer, fp16 intermediates, f32 accumulation.
// per layer: h = (x*ns) @ W ; agg = scatter_sum_dst(h[src]) ; out = agg*nd + b ; relu(0,1)
// norm_src folded into agg epilogue of previous layer (relu(x)*s == relu(x*s), s>0).

// ---------------- utility ----------------
__global__ void k_zero_i32(int* __restrict__ p, int n) {
    int i = blockIdx.x * blockDim.x + threadIdx.x;
    int stride = gridDim.x * blockDim.x;
    for (; i < n; i += stride) p[i] = 0;
}

// ---------------- degree histogram ----------------
__global__ void k_degrees(const int* __restrict__ src, const int* __restrict__ dst, int E,
                          int* __restrict__ deg_o, int* __restrict__ deg_i) {
    int i = blockIdx.x * blockDim.x + threadIdx.x;
    int stride = gridDim.x * blockDim.x;
    for (; i < E; i += stride) {
        atomicAdd(&deg_o[src[i]], 1);
        atomicAdd(&deg_i[dst[i]], 1);
    }
}

__global__ void k_norms(const int* __restrict__ deg_o, const int* __restrict__ deg_i,
                        float* __restrict__ ns, float* __restrict__ nd, int n) {
    int i = blockIdx.x * blockDim.x + threadIdx.x;
    if (i < n) {
        ns[i] = rsqrtf((float)max(deg_o[i], 1));
        nd[i] = rsqrtf((float)max(deg_i[i], 1));
    }
}

// ---------------- hierarchical exclusive scan (row_ptr) ----------------
__global__ __launch_bounds__(256) void k_scan1(const int* __restrict__ deg,
                                               int* __restrict__ rp,
                                               int* __restrict__ bsum, int n) {
    const int tid = threadIdx.x, lane = tid & 63, wid = tid >> 6;
    int i = blockIdx.x * 256 + tid;
    int v = (i < n) ? deg[i] : 0;
    int x = v;
#pragma unroll
    for (int off = 1; off < 64; off <<= 1) {
        int t = __shfl_up(x, off, 64);
        if (lane >= off) x += t;
    }
    __shared__ int ws[4];
    if (lane == 63) ws[wid] = x;
    __syncthreads();
    int wo = 0;
    for (int k = 0; k < wid; ++k) wo += ws[k];
    int incl = wo + x;
    if (i < n) rp[i] = incl - v;  // block-local exclusive
    if (tid == 255) bsum[blockIdx.x] = incl;  // block total
}

__global__ __launch_bounds__(512) void k_scan2(int* __restrict__ bsum, int nb,
                                               int* __restrict__ rpN) {
    __shared__ int s[512];
    const int tid = threadIdx.x;
    int v = (tid < nb) ? bsum[tid] : 0;
    s[tid] = v;
    __syncthreads();
    for (int off = 1; off < 512; off <<= 1) {
        int t = (tid >= off) ? s[tid - off] : 0;
        __syncthreads();
        s[tid] += t;
        __syncthreads();
    }
    if (tid < nb) bsum[tid] = s[tid] - v;  // exclusive
    if (tid == nb - 1) *rpN = s[tid];      // grand total -> rp[N]
}

__global__ void k_scan3(int* __restrict__ rp, const int* __restrict__ bsum, int n) {
    int i = blockIdx.x * blockDim.x + threadIdx.x;
    if (i < n) rp[i] += bsum[i >> 8];
}

// ---------------- CSR fill (grouped by dst) ----------------
__global__ void k_fill(const int* __restrict__ src, const int* __restrict__ dst, int E,
                       const int* __restrict__ rp, int* __restrict__ fill,
                       int* __restrict__ csr_src) {
    int i = blockIdx.x * blockDim.x + threadIdx.x;
    int stride = gridDim.x * blockDim.x;
    for (; i < E; i += stride) {
        int d = dst[i];
        int p = rp[d] + atomicAdd(&fill[d], 1);
        csr_src[p] = src[i];
    }
}

// ---------------- GEMM variants ----------------
// layer 0: A f32 (feat), scaled by ns, W f32, C fp16.  BN=128.
template <int BN, int TM, int TN>
__global__ __launch_bounds__(256) void k_gemm_f32in(const float* __restrict__ A,
                                                    const float* __restrict__ ns,
                                                    const float* __restrict__ W,
                                                    __half* __restrict__ C, int n) {
    constexpr int BM = 64, BK = 32, K = 128;
    constexpr int TCOLS = BN / TN;
    constexpr int TROWS = 256 / TCOLS;
    static_assert(TM == BM / TROWS, "tile mismatch");
    __shared__ float As[BK][BM + 4];
    __shared__ float Ws[BK][BN + 4];
    const int tid = threadIdx.x;
    const int row0 = blockIdx.x * BM;
    const int tc = tid % TCOLS, tr = tid / TCOLS;
    float acc[TM][TN] = {};
    for (int k0 = 0; k0 < K; k0 += BK) {
#pragma unroll
        for (int f = 0; f < (BM * BK / 4) / 256; ++f) {
            int idx = tid + f * 256;
            int r = idx >> 3, c = idx & 7;
            float4 v = make_float4(0.f, 0.f, 0.f, 0.f);
            int gr = row0 + r;
            if (gr < n) {
                v = *(const float4*)(A + (size_t)gr * K + k0 + c * 4);
                float s = ns[gr];
                v.x *= s; v.y *= s; v.z *= s; v.w *= s;
            }
            As[c * 4 + 0][r] = v.x;
            As[c * 4 + 1][r] = v.y;
            As[c * 4 + 2][r] = v.z;
            As[c * 4 + 3][r] = v.w;
        }
#pragma unroll
        for (int f = 0; f < (BK * BN / 4) / 256; ++f) {
            int idx = tid + f * 256;
            int kr = idx / (BN / 4), c4 = idx % (BN / 4);
            *(float4*)&Ws[kr][c4 * 4] = *(const float4*)(W + (size_t)(k0 + kr) * BN + c4 * 4);
        }
        __syncthreads();
#pragma unroll
        for (int kk = 0; kk < BK; ++kk) {
            float a[TM], w[TN];
#pragma unroll
            for (int m = 0; m < TM; ++m) a[m] = As[kk][tr * TM + m];
#pragma unroll
            for (int j = 0; j < TN; ++j) w[j] = Ws[kk][tc * TN + j];
#pragma unroll
            for (int m = 0; m < TM; ++m)
#pragma unroll
                for (int j = 0; j < TN; ++j) acc[m][j] += a[m] * w[j];
        }
        __syncthreads();
    }
#pragma unroll
    for (int m = 0; m < TM; ++m) {
        int gr = row0 + tr * TM + m;
        if (gr < n) {
            __half2 h0 = __floats2half2_rn(acc[m][0], acc[m][1]);
            __half2 h1 = __floats2half2_rn(acc[m][2], acc[m][3]);
            uint2 packed = make_uint2(*(unsigned*)&h0, *(unsigned*)&h1);
            *(uint2*)(C + (size_t)gr * BN + tc * TN) = packed;
        }
    }
}

// layers 1,2: A fp16 (pre-scaled), W f32, C fp16.
template <int BN, int TM, int TN>
__global__ __launch_bounds__(256) void k_gemm_h16in(const __half* __restrict__ A,
                                                    const float* __restrict__ W,
                                                    __half* __restrict__ C, int n) {
    constexpr int BM = 64, BK = 32, K = 128;
    constexpr int TCOLS = BN / TN;
    constexpr int TROWS = 256 / TCOLS;
    static_assert(TM == BM / TROWS, "tile mismatch");
    __shared__ float As[BK][BM + 4];
    __shared__ float Ws[BK][BN + 4];
    const int tid = threadIdx.x;
    const int row0 = blockIdx.x * BM;
    const int tc = tid % TCOLS, tr = tid / TCOLS;
    float acc[TM][TN] = {};
    for (int k0 = 0; k0 < K; k0 += BK) {
        // A tile: 64 rows x 32 halves = 2048 halves = 256 threads x 8 halves
        {
            int r = tid >> 2, c = tid & 3;  // c: chunk of 8 halves
            int gr = row0 + r;
            float4 raw = make_float4(0.f, 0.f, 0.f, 0.f);
            if (gr < n) raw = *(const float4*)(A + (size_t)gr * K + k0 + c * 8);
            __half2* hp = (__half2*)&raw;
#pragma unroll
            for (int j = 0; j < 4; ++j) {
                float2 f = __half22float2(hp[j]);
                As[c * 8 + 2 * j + 0][r] = f.x;
                As[c * 8 + 2 * j + 1][r] = f.y;
            }
        }
#pragma unroll
        for (int f = 0; f < (BK * BN / 4) / 256; ++f) {
            int idx = tid + f * 256;
            int kr = idx / (BN / 4), c4 = idx % (BN / 4);
            *(float4*)&Ws[kr][c4 * 4] = *(const float4*)(W + (size_t)(k0 + kr) * BN + c4 * 4);
        }
        __syncthreads();
#pragma unroll
        for (int kk = 0; kk < BK; ++kk) {
            float a[TM], w[TN];
#pragma unroll
            for (int m = 0; m < TM; ++m) a[m] = As[kk][tr * TM + m];
#pragma unroll
            for (int j = 0; j < TN; ++j) w[j] = Ws[kk][tc * TN + j];
#pragma unroll
            for (int m = 0; m < TM; ++m)
#pragma unroll
                for (int j = 0; j < TN; ++j) acc[m][j] += a[m] * w[j];
        }
        __syncthreads();
    }
#pragma unroll
    for (int m = 0; m < TM; ++m) {
        int gr = row0 + tr * TM + m;
        if (gr < n) {
            __half2 h0 = __floats2half2_rn(acc[m][0], acc[m][1]);
            __half2 h1 = __floats2half2_rn(acc[m][2], acc[m][3]);
            uint2 packed = make_uint2(*(unsigned*)&h0, *(unsigned*)&h1);
            *(uint2*)(C + (size_t)gr * BN + tc * TN) = packed;
        }
    }
}

// ---------------- aggregation D=128 fp16 in, fp16 out (pre-scaled by ns) ----------------
template <bool RELU>
__global__ __launch_bounds__(256) void k_agg128h(const __half2* __restrict__ H,  // [N][64] half2
                                                 const int* __restrict__ rp,
                                                 const int* __restrict__ cs,
                                                 const float* __restrict__ nd,
                                                 const float* __restrict__ ns,
                                                 const float* __restrict__ b,
                                                 __half2* __restrict__ out, int n) {
    const int wid = threadIdx.x >> 6, lane = threadIdx.x & 63;
    const int node = blockIdx.x * 4 + wid;
    if (node >= n) return;
    const int beg = rp[node], end = rp[node + 1];
    float2 a0 = make_float2(0.f, 0.f), a1 = a0, a2 = a0, a3 = a0;
    int e = beg;
    for (; e + 3 < end; e += 4) {
        int s0 = cs[e], s1 = cs[e + 1], s2 = cs[e + 2], s3 = cs[e + 3];
        float2 v0 = __half22float2(H[(size_t)s0 * 64 + lane]);
        float2 v1 = __half22float2(H[(size_t)s1 * 64 + lane]);
        float2 v2 = __half22float2(H[(size_t)s2 * 64 + lane]);
        float2 v3 = __half22float2(H[(size_t)s3 * 64 + lane]);
        a0.x += v0.x; a0.y += v0.y;
        a1.x += v1.x; a1.y += v1.y;
        a2.x += v2.x; a2.y += v2.y;
        a3.x += v3.x; a3.y += v3.y;
    }
    for (; e < end; ++e) {
        float2 v0 = __half22float2(H[(size_t)cs[e] * 64 + lane]);
        a0.x += v0.x; a0.y += v0.y;
    }
    const float sc = nd[node];
    const float sn = ns[node];
    float2 bb = ((const float2*)b)[lane];
    float ox = (a0.x + a1.x + a2.x + a3.x) * sc + bb.x;
    float oy = (a0.y + a1.y + a2.y + a3.y) * sc + bb.y;
    if (RELU) { ox = fmaxf(ox, 0.f); oy = fmaxf(oy, 0.f); }
    ox *= sn; oy *= sn;
    out[(size_t)node * 64 + lane] = __floats2half2_rn(ox, oy);
}

// ---------------- aggregation D=64 fp16 in, f32 out, no relu, no ns fold ----------------
__global__ __launch_bounds__(256) void k_agg64h(const __half* __restrict__ H,  // [N][64]
                                                const int* __restrict__ rp,
                                                const int* __restrict__ cs,
                                                const float* __restrict__ nd,
                                                const float* __restrict__ b,
                                                float* __restrict__ out, int n) {
    const int wid = threadIdx.x >> 6, lane = threadIdx.x & 63;
    const int node = blockIdx.x * 4 + wid;
    if (node >= n) return;
    const int beg = rp[node], end = rp[node + 1];
    float a0 = 0.f, a1 = 0.f, a2 = 0.f, a3 = 0.f;
    int e = beg;
    for (; e + 3 < end; e += 4) {
        a0 += __half2float(H[(size_t)cs[e] * 64 + lane]);
        a1 += __half2float(H[(size_t)cs[e + 1] * 64 + lane]);
        a2 += __half2float(H[(size_t)cs[e + 2] * 64 + lane]);
        a3 += __half2float(H[(size_t)cs[e + 3] * 64 + lane]);
    }
    for (; e < end; ++e) a0 += __half2float(H[(size_t)cs[e] * 64 + lane]);
    out[(size_t)node * 64 + lane] = (a0 + a1 + a2 + a3) * nd[node] + b[lane];
}

extern "C" void kernel_launch(void* const* d_in, const int* in_sizes, int n_in,
                              void* d_out, int out_size, void* d_ws, size_t ws_size,
                              hipStream_t stream) {
    const float* feat = (const float*)d_in[0];
    const int* ei = (const int*)d_in[1];
    const float* W0 = (const float*)d_in[2];
    const float* b0 = (const float*)d_in[3];
    const float* W1 = (const float*)d_in[4];
    const float* b1 = (const float*)d_in[5];
    const float* W2 = (const float*)d_in[6];
    const float* b2 = (const float*)d_in[7];
    float* out = (float*)d_out;

    const int N = in_sizes[0] / 128;  // 100000
    const int E = in_sizes[1] / 2;    // 1600000
    const int* src = ei;
    const int* dst = ei + E;
    const int NB = (N + 255) / 256;   // scan blocks (391 <= 512)

    // workspace layout
    char* w = (char*)d_ws;
    float* norm_src = (float*)w; w += (size_t)N * 4;
    float* norm_dst = (float*)w; w += (size_t)N * 4;
    int* deg_o = (int*)w;        w += (size_t)N * 4;
    int* deg_i = (int*)w;        w += (size_t)N * 4;
    int* fill  = (int*)w;        w += (size_t)N * 4;   // deg_o,deg_i,fill contiguous
    int* rp    = (int*)w;        w += ((size_t)(N + 1) * 4 + 15) / 16 * 16;
    int* bsum  = (int*)w;        w += 512 * 4;
    int* csr   = (int*)w;        w += (size_t)E * 4;
    __half* bufH = (__half*)w;   w += (size_t)N * 128 * 2;  // GEMM out (gather src)
    __half* bufX = (__half*)w;   w += (size_t)N * 128 * 2;  // next-layer input (pre-scaled)

    // CSR build
    k_zero_i32<<<512, 256, 0, stream>>>(deg_o, 3 * N);
    k_degrees<<<2048, 256, 0, stream>>>(src, dst, E, deg_o, deg_i);
    k_norms<<<(N + 255) / 256, 256, 0, stream>>>(deg_o, deg_i, norm_src, norm_dst, N);
    k_scan1<<<NB, 256, 0, stream>>>(deg_i, rp, bsum, N);
    k_scan2<<<1, 512, 0, stream>>>(bsum, NB, rp + N);
    k_scan3<<<NB, 256, 0, stream>>>(rp, bsum, N);
    k_fill<<<2048, 256, 0, stream>>>(src, dst, E, rp, fill, csr);

    const int gemm_grid = (N + 63) / 64;
    const int agg_grid = (N + 3) / 4;

    // layer 0: feat(f32)*ns @ W0 -> H(fp16); agg -> X(fp16, pre-scaled by ns), relu
    k_gemm_f32in<128, 8, 4><<<gemm_grid, 256, 0, stream>>>(feat, norm_src, W0, bufH, N);
    k_agg128h<true><<<agg_grid, 256, 0, stream>>>((const __half2*)bufH, rp, csr, norm_dst,
                                                  norm_src, b0, (__half2*)bufX, N);
    // layer 1
    k_gemm_h16in<128, 8, 4><<<gemm_grid, 256, 0, stream>>>(bufX, W1, bufH, N);
    k_agg128h<true><<<agg_grid, 256, 0, stream>>>((const __half2*)bufH, rp, csr, norm_dst,
                                                  norm_src, b1, (__half2*)bufX, N);
    // layer 2: out dim 64, no relu, f32 out
    k_gemm_h16in<64, 4, 4><<<gemm_grid, 256, 0, stream>>>(bufX, W2, bufH, N);
    k_agg64h<<<agg_grid, 256, 0, stream>>>(bufH, rp, csr, norm_dst, b2, out, N);
}

// Round 6
// 485.553 us; speedup vs baseline: 1.7651x; 1.2377x over previous
//
#include <hip/hip_runtime.h>
#include <hip/hip_fp16.h>

// GCN 3-layer, fp16 intermediates, f32 accum, MFMA GEMMs, atomic-lean CSR build.
// per layer: h = (x*ns) @ W ; agg = scatter_sum_dst(h[src]) ; out = agg*nd + b ; relu(0,1)
// norm_src folded into agg epilogue of previous layer (relu(x)*s == relu(x*s), s>0).

typedef _Float16 h8 __attribute__((ext_vector_type(8)));
typedef float f32x4 __attribute__((ext_vector_type(4)));

// ---------------- utility ----------------
__global__ void k_zero_i32(int* __restrict__ p, int n) {
    int i = blockIdx.x * blockDim.x + threadIdx.x;
    int stride = gridDim.x * blockDim.x;
    for (; i < n; i += stride) p[i] = 0;
}

// ---------------- count degrees + capture per-edge position ----------------
__global__ void k_count(const int* __restrict__ src, const int* __restrict__ dst, int E,
                        int* __restrict__ deg_o, int* __restrict__ deg_i,
                        int* __restrict__ pos) {
    int i = blockIdx.x * blockDim.x + threadIdx.x;
    int stride = gridDim.x * blockDim.x;
    for (; i < E; i += stride) {
        atomicAdd(&deg_o[src[i]], 1);
        pos[i] = atomicAdd(&deg_i[dst[i]], 1);
    }
}

__global__ void k_norms(const int* __restrict__ deg_o, const int* __restrict__ deg_i,
                        float* __restrict__ ns, float* __restrict__ nd, int n) {
    int i = blockIdx.x * blockDim.x + threadIdx.x;
    if (i < n) {
        ns[i] = rsqrtf((float)max(deg_o[i], 1));
        nd[i] = rsqrtf((float)max(deg_i[i], 1));
    }
}

// ---------------- hierarchical exclusive scan (row_ptr) ----------------
__global__ __launch_bounds__(256) void k_scan1(const int* __restrict__ deg,
                                               int* __restrict__ rp,
                                               int* __restrict__ bsum, int n) {
    const int tid = threadIdx.x, lane = tid & 63, wid = tid >> 6;
    int i = blockIdx.x * 256 + tid;
    int v = (i < n) ? deg[i] : 0;
    int x = v;
#pragma unroll
    for (int off = 1; off < 64; off <<= 1) {
        int t = __shfl_up(x, off, 64);
        if (lane >= off) x += t;
    }
    __shared__ int ws[4];
    if (lane == 63) ws[wid] = x;
    __syncthreads();
    int wo = 0;
    for (int k = 0; k < wid; ++k) wo += ws[k];
    int incl = wo + x;
    if (i < n) rp[i] = incl - v;  // block-local exclusive
    if (tid == 255) bsum[blockIdx.x] = incl;  // block total
}

__global__ __launch_bounds__(512) void k_scan2(int* __restrict__ bsum, int nb,
                                               int* __restrict__ rpN) {
    __shared__ int s[512];
    const int tid = threadIdx.x;
    int v = (tid < nb) ? bsum[tid] : 0;
    s[tid] = v;
    __syncthreads();
    for (int off = 1; off < 512; off <<= 1) {
        int t = (tid >= off) ? s[tid - off] : 0;
        __syncthreads();
        s[tid] += t;
        __syncthreads();
    }
    if (tid < nb) bsum[tid] = s[tid] - v;  // exclusive
    if (tid == nb - 1) *rpN = s[tid];      // grand total -> rp[N]
}

__global__ void k_scan3(int* __restrict__ rp, const int* __restrict__ bsum, int n) {
    int i = blockIdx.x * blockDim.x + threadIdx.x;
    if (i < n) rp[i] += bsum[i >> 8];
}

// ---------------- CSR scatter (no atomics) ----------------
__global__ void k_scatter(const int* __restrict__ src, const int* __restrict__ dst, int E,
                          const int* __restrict__ rp, const int* __restrict__ pos,
                          int* __restrict__ csr_src) {
    int i = blockIdx.x * blockDim.x + threadIdx.x;
    int stride = gridDim.x * blockDim.x;
    for (; i < E; i += stride) {
        csr_src[rp[dst[i]] + pos[i]] = src[i];
    }
}

// ---------------- weight prep: Wt[n][k] = (half)W[k][n] ----------------
__global__ void k_prepW(const float* __restrict__ W, __half* __restrict__ Wt,
                        int K, int BN) {
    int idx = blockIdx.x * blockDim.x + threadIdx.x;
    if (idx < K * BN) {
        int n = idx / K, k = idx % K;
        Wt[idx] = __float2half(W[k * BN + n]);
    }
}

// ---------------- layer-0 input prep: X[i] = (half)(feat[i] * ns[row]) ----------------
__global__ void k_prepX0(const float* __restrict__ feat, const float* __restrict__ ns,
                         __half* __restrict__ X, int n) {
    int i = blockIdx.x * blockDim.x + threadIdx.x;  // float4 index
    int total = n * 32;                             // N*128/4
    int stride = gridDim.x * blockDim.x;
    for (; i < total; i += stride) {
        int row = i >> 5;
        float s = ns[row];
        float4 v = ((const float4*)feat)[i];
        __half2 h0 = __floats2half2_rn(v.x * s, v.y * s);
        __half2 h1 = __floats2half2_rn(v.z * s, v.w * s);
        uint2 packed = make_uint2(*(unsigned*)&h0, *(unsigned*)&h1);
        *(uint2*)(X + (size_t)i * 4) = packed;
    }
}

// ---------------- MFMA GEMM: C[n,BN] = X[n,128] @ Wt[BN,128]^T, fp16 in/out ----------------
// v_mfma_f32_16x16x32_f16: A/B frag = 8 contiguous-K halves/lane at k=8*(lane>>4),
// row/col = lane&15. C/D: col=lane&15, row=(lane>>4)*4+reg (guide m89-verified).
template <int BN>
__global__ __launch_bounds__(256) void k_gemm_mfma(const __half* __restrict__ X,
                                                   const __half* __restrict__ Wt,
                                                   __half* __restrict__ C, int n) {
    constexpr int K = 128, BM = 128, PAD = 8, LDR = K + PAD;  // halves
    __shared__ __half Al[BM * LDR];
    __shared__ __half Bl[BN * LDR];
    const int tid = threadIdx.x;
    const int row0 = blockIdx.x * BM;
    // stage A tile (BM x 128 halves), fully coalesced 16B chunks
    {
        const float4 z = make_float4(0.f, 0.f, 0.f, 0.f);
#pragma unroll
        for (int q = 0; q < 8; ++q) {
            int fi = q * 256 + tid;            // float4 index within tile
            int r = fi >> 4, c = (fi & 15) * 8;
            int gr = row0 + r;
            float4 v = (gr < n) ? *(const float4*)(X + (size_t)gr * K + c) : z;
            *(float4*)&Al[r * LDR + c] = v;
        }
    }
    // stage Wt tile (BN x 128 halves)
    {
#pragma unroll
        for (int q = 0; q < BN / 16; ++q) {
            int fi = q * 256 + tid;
            int r = fi >> 4, c = (fi & 15) * 8;
            *(float4*)&Bl[r * LDR + c] = *(const float4*)(Wt + (size_t)r * K + c);
        }
    }
    __syncthreads();
    const int wid = tid >> 6, lane = tid & 63;
    const int lo = lane & 15, hi = lane >> 4;
    constexpr int NC = BN / 16;
    f32x4 acc[2][NC];
#pragma unroll
    for (int t = 0; t < 2; ++t)
#pragma unroll
        for (int c = 0; c < NC; ++c) acc[t][c] = (f32x4){0.f, 0.f, 0.f, 0.f};
#pragma unroll
    for (int kc = 0; kc < 4; ++kc) {
        h8 aF[2];
#pragma unroll
        for (int t = 0; t < 2; ++t)
            aF[t] = *(const h8*)&Al[(32 * wid + 16 * t + lo) * LDR + 32 * kc + 8 * hi];
#pragma unroll
        for (int c = 0; c < NC; ++c) {
            h8 bF = *(const h8*)&Bl[(16 * c + lo) * LDR + 32 * kc + 8 * hi];
#pragma unroll
            for (int t = 0; t < 2; ++t)
                acc[t][c] = __builtin_amdgcn_mfma_f32_16x16x32_f16(aF[t], bF, acc[t][c], 0, 0, 0);
        }
    }
    // store: row = row0 + 32*wid + 16*t + 4*hi + j, col = 16*c + lo
#pragma unroll
    for (int t = 0; t < 2; ++t) {
#pragma unroll
        for (int j = 0; j < 4; ++j) {
            int gr = row0 + 32 * wid + 16 * t + 4 * hi + j;
            if (gr < n) {
#pragma unroll
                for (int c = 0; c < NC; ++c)
                    C[(size_t)gr * BN + 16 * c + lo] = __float2half(acc[t][c][j]);
            }
        }
    }
}

// ---------------- aggregation D=128 fp16 in, fp16 out (pre-scaled by ns) ----------------
template <bool RELU>
__global__ __launch_bounds__(256) void k_agg128h(const __half2* __restrict__ H,  // [N][64] half2
                                                 const int* __restrict__ rp,
                                                 const int* __restrict__ cs,
                                                 const float* __restrict__ nd,
                                                 const float* __restrict__ ns,
                                                 const float* __restrict__ b,
                                                 __half2* __restrict__ out, int n) {
    const int wid = threadIdx.x >> 6, lane = threadIdx.x & 63;
    const int node = blockIdx.x * 4 + wid;
    if (node >= n) return;
    const int beg = rp[node], end = rp[node + 1];
    float2 a0 = make_float2(0.f, 0.f), a1 = a0, a2 = a0, a3 = a0;
    int e = beg;
    for (; e + 3 < end; e += 4) {
        int s0 = cs[e], s1 = cs[e + 1], s2 = cs[e + 2], s3 = cs[e + 3];
        float2 v0 = __half22float2(H[(size_t)s0 * 64 + lane]);
        float2 v1 = __half22float2(H[(size_t)s1 * 64 + lane]);
        float2 v2 = __half22float2(H[(size_t)s2 * 64 + lane]);
        float2 v3 = __half22float2(H[(size_t)s3 * 64 + lane]);
        a0.x += v0.x; a0.y += v0.y;
        a1.x += v1.x; a1.y += v1.y;
        a2.x += v2.x; a2.y += v2.y;
        a3.x += v3.x; a3.y += v3.y;
    }
    for (; e < end; ++e) {
        float2 v0 = __half22float2(H[(size_t)cs[e] * 64 + lane]);
        a0.x += v0.x; a0.y += v0.y;
    }
    const float sc = nd[node];
    const float sn = ns[node];
    float2 bb = ((const float2*)b)[lane];
    float ox = (a0.x + a1.x + a2.x + a3.x) * sc + bb.x;
    float oy = (a0.y + a1.y + a2.y + a3.y) * sc + bb.y;
    if (RELU) { ox = fmaxf(ox, 0.f); oy = fmaxf(oy, 0.f); }
    ox *= sn; oy *= sn;
    out[(size_t)node * 64 + lane] = __floats2half2_rn(ox, oy);
}

// ---------------- aggregation D=64 fp16 in, f32 out, no relu, no ns fold ----------------
__global__ __launch_bounds__(256) void k_agg64h(const __half* __restrict__ H,  // [N][64]
                                                const int* __restrict__ rp,
                                                const int* __restrict__ cs,
                                                const float* __restrict__ nd,
                                                const float* __restrict__ b,
                                                float* __restrict__ out, int n) {
    const int wid = threadIdx.x >> 6, lane = threadIdx.x & 63;
    const int node = blockIdx.x * 4 + wid;
    if (node >= n) return;
    const int beg = rp[node], end = rp[node + 1];
    float a0 = 0.f, a1 = 0.f, a2 = 0.f, a3 = 0.f;
    int e = beg;
    for (; e + 3 < end; e += 4) {
        a0 += __half2float(H[(size_t)cs[e] * 64 + lane]);
        a1 += __half2float(H[(size_t)cs[e + 1] * 64 + lane]);
        a2 += __half2float(H[(size_t)cs[e + 2] * 64 + lane]);
        a3 += __half2float(H[(size_t)cs[e + 3] * 64 + lane]);
    }
    for (; e < end; ++e) a0 += __half2float(H[(size_t)cs[e] * 64 + lane]);
    out[(size_t)node * 64 + lane] = (a0 + a1 + a2 + a3) * nd[node] + b[lane];
}

extern "C" void kernel_launch(void* const* d_in, const int* in_sizes, int n_in,
                              void* d_out, int out_size, void* d_ws, size_t ws_size,
                              hipStream_t stream) {
    const float* feat = (const float*)d_in[0];
    const int* ei = (const int*)d_in[1];
    const float* W0 = (const float*)d_in[2];
    const float* b0 = (const float*)d_in[3];
    const float* W1 = (const float*)d_in[4];
    const float* b1 = (const float*)d_in[5];
    const float* W2 = (const float*)d_in[6];
    const float* b2 = (const float*)d_in[7];
    float* out = (float*)d_out;

    const int N = in_sizes[0] / 128;  // 100000
    const int E = in_sizes[1] / 2;    // 1600000
    const int* src = ei;
    const int* dst = ei + E;
    const int NB = (N + 255) / 256;   // scan blocks (391 <= 512)

    // workspace layout (16B-aligned chunks)
    char* w = (char*)d_ws;
    float* norm_src = (float*)w; w += (size_t)N * 4;
    float* norm_dst = (float*)w; w += (size_t)N * 4;
    int* deg_o = (int*)w;        w += (size_t)N * 4;   // deg_o,deg_i contiguous (zero 2N)
    int* deg_i = (int*)w;        w += (size_t)N * 4;
    int* rp    = (int*)w;        w += ((size_t)(N + 1) * 4 + 15) / 16 * 16;
    int* bsum  = (int*)w;        w += 512 * 4;
    int* pos   = (int*)w;        w += (size_t)E * 4;
    int* csr   = (int*)w;        w += (size_t)E * 4;
    __half* Wt0 = (__half*)w;    w += 128 * 128 * 2;
    __half* Wt1 = (__half*)w;    w += 128 * 128 * 2;
    __half* Wt2 = (__half*)w;    w += 128 * 64 * 2;
    __half* Xb = (__half*)w;     w += (size_t)N * 128 * 2;  // GEMM input
    __half* Hb = (__half*)w;     w += (size_t)N * 128 * 2;  // GEMM output (gather src)

    // ---- CSR build (one atomic pass) ----
    k_zero_i32<<<512, 256, 0, stream>>>(deg_o, 2 * N);
    k_count<<<2048, 256, 0, stream>>>(src, dst, E, deg_o, deg_i, pos);
    k_norms<<<NB, 256, 0, stream>>>(deg_o, deg_i, norm_src, norm_dst, N);
    k_scan1<<<NB, 256, 0, stream>>>(deg_i, rp, bsum, N);
    k_scan2<<<1, 512, 0, stream>>>(bsum, NB, rp + N);
    k_scan3<<<NB, 256, 0, stream>>>(rp, bsum, N);
    k_scatter<<<2048, 256, 0, stream>>>(src, dst, E, rp, pos, csr);

    // ---- weight / input prep ----
    k_prepW<<<(128 * 128 + 255) / 256, 256, 0, stream>>>(W0, Wt0, 128, 128);
    k_prepW<<<(128 * 128 + 255) / 256, 256, 0, stream>>>(W1, Wt1, 128, 128);
    k_prepW<<<(128 * 64 + 255) / 256, 256, 0, stream>>>(W2, Wt2, 128, 64);
    k_prepX0<<<2048, 256, 0, stream>>>(feat, norm_src, Xb, N);

    const int gemm_grid = (N + 127) / 128;
    const int agg_grid = (N + 3) / 4;

    // layer 0
    k_gemm_mfma<128><<<gemm_grid, 256, 0, stream>>>(Xb, Wt0, Hb, N);
    k_agg128h<true><<<agg_grid, 256, 0, stream>>>((const __half2*)Hb, rp, csr, norm_dst,
                                                  norm_src, b0, (__half2*)Xb, N);
    // layer 1
    k_gemm_mfma<128><<<gemm_grid, 256, 0, stream>>>(Xb, Wt1, Hb, N);
    k_agg128h<true><<<agg_grid, 256, 0, stream>>>((const __half2*)Hb, rp, csr, norm_dst,
                                                  norm_src, b1, (__half2*)Xb, N);
    // layer 2 (BN=64, no relu, f32 out)
    k_gemm_mfma<64><<<gemm_grid, 256, 0, stream>>>(Xb, Wt2, Hb, N);
    k_agg64h<<<agg_grid, 256, 0, stream>>>(Hb, rp, csr, norm_dst, b2, out, N);
}